// Round 4
// baseline (265.254 us; speedup 1.0000x reference)
//
#include <hip/hip_runtime.h>
#include <hip/hip_bf16.h>
#include <math.h>

#define HW   3136
#define NIMG 64
#define M_TOT (NIMG * HW)   // 200704

typedef __attribute__((ext_vector_type(8))) short bf16x8_t;
typedef __attribute__((ext_vector_type(4))) float f32x4_t;

__device__ __forceinline__ unsigned short f2bf(float f) {
  union { float f; unsigned u; } v; v.f = f;
  unsigned r = v.u + 0x7FFFu + ((v.u >> 16) & 1u);
  return (unsigned short)(r >> 16);
}
__device__ __forceinline__ float bf2f(unsigned short h) {
  union { unsigned u; float f; } v; v.u = ((unsigned)h) << 16;
  return v.f;
}

// ---------------- K0: swizzle weight [N][K] into MFMA B-fragment order ----
// frag fi = nt*(K/32)+kt ; element j of lane l <-> n = nt*16+(l&15),
// k = kt*32 + (l>>4)*8 + j.
__global__ void k0_swz(const float* __restrict__ wsrc, unsigned short* __restrict__ bsw,
                       int N, int K) {
  int idx = blockIdx.x * 256 + threadIdx.x;
  int total = (N / 16) * (K / 32) * 64;
  if (idx >= total) return;
  int l  = idx & 63;
  int fi = idx >> 6;
  int KT = K / 32;
  int nt = fi / KT, kt = fi - nt * KT;
  int nn = nt * 16 + (l & 15);
  int kb = kt * 32 + (l >> 4) * 8;
  const float* src = wsrc + (size_t)nn * K + kb;
  unsigned short* dst = bsw + (size_t)idx * 8;
#pragma unroll
  for (int j = 0; j < 8; j++) dst[j] = f2bf(src[j]);
}

// ---------------- K0c: fold GRN beta through w2 into bias ---------------
__global__ void k0_b2p(const float* __restrict__ w2, const float* __restrict__ grnb,
                       const float* __restrict__ b2, float* __restrict__ b2p) {
  int c = blockIdx.x * blockDim.x + threadIdx.x;
  if (c >= 96) return;
  float s = b2[c];
  const float* wr = w2 + (size_t)c * 384;
  for (int f = 0; f < 384; f++) s += grnb[f] * wr[f];
  b2p[c] = s;
}

// ---------------- K1a: depthwise 7x7 conv, one (n,c) plane per block ----
template<int ROWS>
__device__ __forceinline__ void dw_block(const float (*xs)[65], const float (&w)[49],
                                         float bias, int y0, int xc, float (&acc)[ROWS]) {
  float win[ROWS + 6][7];
#pragma unroll
  for (int rr = 0; rr < ROWS + 6; rr++)
#pragma unroll
    for (int dx = 0; dx < 7; dx++)
      win[rr][dx] = xs[y0 + rr][xc + dx];
#pragma unroll
  for (int py = 0; py < ROWS; py++) acc[py] = bias;
#pragma unroll
  for (int dy = 0; dy < 7; dy++)
#pragma unroll
    for (int dx = 0; dx < 7; dx++) {
      float wv = w[dy * 7 + dx];
#pragma unroll
      for (int py = 0; py < ROWS; py++)
        acc[py] = fmaf(wv, win[py + dy][dx], acc[py]);
    }
}

__global__ __launch_bounds__(256) void k1a_dwconv(
    const float* __restrict__ x, const float* __restrict__ dww,
    const float* __restrict__ dwb, unsigned short* __restrict__ conv) {
  __shared__ float xs[62][65];
  const int c = blockIdx.x, n = blockIdx.y;
  const int t = threadIdx.x;
  const float* xp = x + ((size_t)n * 96 + c) * HW;
  for (int i = t; i < 62 * 64; i += 256) {
    int r = i >> 6, col = i & 63;
    if (col < 62) {
      int h = r - 3, w = col - 3;
      float v = ((unsigned)h < 56u && (unsigned)w < 56u) ? xp[h * 56 + w] : 0.f;
      xs[r][col] = v;
    }
  }
  float w[49];
#pragma unroll
  for (int j = 0; j < 49; j++) w[j] = dww[c * 49 + j];
  const float bias = dwb[c];
  __syncthreads();
  const int xq = t & 63, yq = t >> 6;
  const int xc = xq < 56 ? xq : 55;
  unsigned short* op = conv + ((size_t)n * 96 + c) * HW + xq;
  const int ybase = yq * 14;
#pragma unroll
  for (int yb = 0; yb < 12; yb += 4) {
    float acc[4];
    dw_block<4>(xs, w, bias, ybase + yb, xc, acc);
    if (xq < 56) {
#pragma unroll
      for (int py = 0; py < 4; py++)
        op[(ybase + yb + py) * 56] = f2bf(acc[py]);
    }
  }
  {
    float acc[2];
    dw_block<2>(xs, w, bias, ybase + 12, xc, acc);
    if (xq < 56) {
#pragma unroll
      for (int py = 0; py < 2; py++)
        op[(ybase + 12 + py) * 56] = f2bf(acc[py]);
    }
  }
}

// ------- K2f: transpose + LN + GEMM1 + GELU + gx2, y1 in FRAG-MAJOR -----
// y1f layout: frag (m16, kt): elems ((m16*12+kt)*64 + l)*8 + j
//             = y1[m16*16 + (l&15)][kt*32 + (l>>4)*8 + j]
__global__ __launch_bounds__(256) void k2f_lngemm1(
    const unsigned short* __restrict__ conv, const float* __restrict__ lng,
    const float* __restrict__ lnb, const unsigned short* __restrict__ B1,
    const float* __restrict__ b1, unsigned short* __restrict__ y1f,
    float* __restrict__ gx2) {
  __shared__ unsigned short smbuf[64 * 392];     // 50 KB, aliased ts/yt
  unsigned short (*ts)[104] = (unsigned short(*)[104])smbuf;
  unsigned short (*yt)[392] = (unsigned short(*)[392])smbuf;
  __shared__ float lnp[192];
  const int t = threadIdx.x;
  const int bid = blockIdx.x;
  const int n = bid / 49;
  const int hw0 = (bid - n * 49) * 64;
  if (t < 192) lnp[t] = (t < 96) ? lng[t] : lnb[t - 96];
  const unsigned short* cp0 = conv + (size_t)n * 96 * HW + hw0;
  for (int i = t; i < 96 * 32; i += 256) {
    int c = i >> 5, pxq = i & 31;
    unsigned u = *(const unsigned*)(cp0 + (size_t)c * HW + pxq * 2);
    ts[pxq * 2 + 0][c] = (unsigned short)(u & 0xffffu);
    ts[pxq * 2 + 1][c] = (unsigned short)(u >> 16);
  }
  __syncthreads();
  // ---- LayerNorm: 4 threads per pixel ----
  {
    const int px = t >> 2, q = t & 3;
    unsigned vu[12];
    float s = 0.f, ss = 0.f;
#pragma unroll
    for (int j = 0; j < 12; j++) {
      vu[j] = *(const unsigned*)&ts[px][q * 24 + j * 2];
      float v0 = bf2f((unsigned short)(vu[j] & 0xffffu));
      float v1 = bf2f((unsigned short)(vu[j] >> 16));
      s += v0 + v1; ss += v0 * v0 + v1 * v1;
    }
    s  += __shfl_xor(s, 1);  s  += __shfl_xor(s, 2);
    ss += __shfl_xor(ss, 1); ss += __shfl_xor(ss, 2);
    float mu  = s * (1.f / 96.f);
    float var = ss * (1.f / 96.f) - mu * mu;
    float rs  = rsqrtf(var + 1e-6f);
#pragma unroll
    for (int j = 0; j < 12; j++) {
      int ch = q * 24 + j * 2;
      float v0 = bf2f((unsigned short)(vu[j] & 0xffffu));
      float v1 = bf2f((unsigned short)(vu[j] >> 16));
      float o0 = (v0 - mu) * rs * lnp[ch] + lnp[96 + ch];
      float o1 = (v1 - mu) * rs * lnp[ch + 1] + lnp[96 + ch + 1];
      *(unsigned*)&ts[px][ch] = (unsigned)f2bf(o0) | ((unsigned)f2bf(o1) << 16);
    }
  }
  __syncthreads();
  // ---- A fragments from ts ----
  const int wv = t >> 6, l = t & 63;
  const int lg = l >> 4, lr = l & 15;
  bf16x8_t af[4][3];
#pragma unroll
  for (int mt = 0; mt < 4; mt++)
#pragma unroll
    for (int kt = 0; kt < 3; kt++)
      af[mt][kt] = *(const bf16x8_t*)&ts[mt * 16 + lr][kt * 32 + lg * 8];
  __syncthreads();   // ts reads drained before yt writes (aliased)

  // ---- GEMM1 + GELU + gx2 ----
  for (int i = 0; i < 6; i++) {
    int nt = wv * 6 + i;
    bf16x8_t bf[3];
#pragma unroll
    for (int kt = 0; kt < 3; kt++)
      bf[kt] = *(const bf16x8_t*)(B1 + ((size_t)(nt * 3 + kt) * 64 + l) * 8);
    f32x4_t acc[4];
#pragma unroll
    for (int mt = 0; mt < 4; mt++) {
      f32x4_t a = {0.f, 0.f, 0.f, 0.f};
#pragma unroll
      for (int kt = 0; kt < 3; kt++)
        a = __builtin_amdgcn_mfma_f32_16x16x32_bf16(af[mt][kt], bf[kt], a, 0, 0, 0);
      acc[mt] = a;
    }
    int f0 = nt * 16;
    float bias = b1[f0 + lr];
    float s2 = 0.f;
#pragma unroll
    for (int mt = 0; mt < 4; mt++) {
#pragma unroll
      for (int r = 0; r < 4; r++) {
        float v = acc[mt][r] + bias;
        float g = 0.5f * v * (1.f + erff(v * 0.70710678118f));
        s2 += g * g;
        yt[mt * 16 + lg * 4 + r][f0 + lr] = f2bf(g);
      }
    }
    s2 += __shfl_xor(s2, 16);
    s2 += __shfl_xor(s2, 32);
    if (l < 16) atomicAdd(gx2 + n * 384 + f0 + l, s2);
  }
  __syncthreads();
  // ---- store y1 in fragment-major order (fully coalesced 1KB/wave) ----
#pragma unroll
  for (int it = 0; it < 12; it++) {
    int id = t + it * 256;               // 3072 = 4 mt * 12 kt * 64 l
    int mt = id / 768, kt = (id >> 6) % 12, ll = id & 63;
    uint4 d = *(const uint4*)&yt[mt * 16 + (ll & 15)][kt * 32 + (ll >> 4) * 8];
    *(uint4*)(y1f + (((size_t)(bid * 4 + mt) * 12 + kt) * 64 + ll) * 8) = d;
  }
}

// -------- K3: GRN coefficients + per-image scaled B2 fragments ----------
__global__ __launch_bounds__(256) void k3_coefB(
    const float* __restrict__ gx2, const float* __restrict__ grng,
    const unsigned short* __restrict__ B2, unsigned short* __restrict__ B2s) {
  __shared__ float red[256];
  __shared__ float cf[384];
  const int n = blockIdx.x, t = threadIdx.x;
  float s = 0.f;
  for (int f = t; f < 384; f += 256) {
    float g = sqrtf(gx2[n * 384 + f]);
    cf[f] = g; s += g;
  }
  red[t] = s; __syncthreads();
  for (int o = 128; o > 0; o >>= 1) {
    if (t < o) red[t] += red[t + o];
    __syncthreads();
  }
  float inv = 1.f / (red[0] * (1.f / 384.f) + 1e-6f);
  for (int f = t; f < 384; f += 256)
    cf[f] = 1.f + grng[f] * cf[f] * inv;
  __syncthreads();
  unsigned short* dstn = B2s + (size_t)n * 36864;
  for (int i = t; i < 4608; i += 256) {        // 4608 uint4 = 36864 elems
    int e0 = i * 8;
    int fi = e0 >> 9, ll = (e0 & 511) >> 3;
    int kb = (fi % 12) * 32 + (ll >> 4) * 8;
    uint4 w = *(const uint4*)(B2 + e0);
    const unsigned* wu = (const unsigned*)&w;
    uint4 o;
    unsigned* ou = (unsigned*)&o;
#pragma unroll
    for (int h = 0; h < 4; h++) {
      float v0 = bf2f((unsigned short)(wu[h] & 0xffffu)) * cf[kb + h * 2];
      float v1 = bf2f((unsigned short)(wu[h] >> 16)) * cf[kb + h * 2 + 1];
      ou[h] = (unsigned)f2bf(v0) | ((unsigned)f2bf(v1) << 16);
    }
    *(uint4*)(dstn + e0) = o;
  }
}

// ---------------- K4: GEMM2 (M x 96 x 384) + residual -------------------
__global__ __launch_bounds__(256) void k4_gemm2(
    const unsigned short* __restrict__ y1f, const unsigned short* __restrict__ B2s,
    const float* __restrict__ b2p, const float* __restrict__ x,
    float* __restrict__ out) {
  __shared__ float zt[96][68];
  const int t  = threadIdx.x;
  const int wv = t >> 6, l = t & 63;
  const int lg = l >> 4, lr = l & 15;
  const int m0 = blockIdx.x * 64;
  const int n  = m0 / HW, hw0 = m0 - n * HW;
  const unsigned short* Bn = B2s + (size_t)n * 36864;

  bf16x8_t af[12];
  const unsigned short* ap = y1f + ((size_t)(blockIdx.x * 4 + wv) * 12) * 512 + l * 8;
#pragma unroll
  for (int kt = 0; kt < 12; kt++)
    af[kt] = *(const bf16x8_t*)(ap + kt * 512);

  f32x4_t acc[6];
#pragma unroll
  for (int i = 0; i < 6; i++) acc[i] = (f32x4_t){0.f, 0.f, 0.f, 0.f};
#pragma unroll
  for (int kt = 0; kt < 12; kt++) {
#pragma unroll
    for (int nt = 0; nt < 6; nt++) {
      bf16x8_t b = *(const bf16x8_t*)(Bn + ((size_t)(nt * 12 + kt) * 64 + l) * 8);
      acc[nt] = __builtin_amdgcn_mfma_f32_16x16x32_bf16(af[kt], b, acc[nt], 0, 0, 0);
    }
  }
#pragma unroll
  for (int nt = 0; nt < 6; nt++) {
    int c = nt * 16 + lr;
#pragma unroll
    for (int r = 0; r < 4; r++)
      zt[c][wv * 16 + lg * 4 + r] = acc[nt][r];
  }
  __syncthreads();
#pragma unroll
  for (int it = 0; it < 6; it++) {
    int id = t + it * 256;  // 1536 = 96 c * 16 quads
    int c = id >> 4, mq = id & 15;
    float4 z = *(const float4*)&zt[c][mq * 4];
    size_t base = ((size_t)(n * 96 + c)) * HW + hw0 + mq * 4;
    float4 xv = *(const float4*)(x + base);
    float bp = b2p[c];
    float4 o;
    o.x = xv.x + z.x + bp;
    o.y = xv.y + z.y + bp;
    o.z = xv.z + z.z + bp;
    o.w = xv.w + z.w + bp;
    *(float4*)(out + base) = o;
  }
}

// ---------------- launch -----------------------------------------------
extern "C" void kernel_launch(void* const* d_in, const int* in_sizes, int n_in,
                              void* d_out, int out_size, void* d_ws, size_t ws_size,
                              hipStream_t stream) {
  const float* x    = (const float*)d_in[0];
  const float* dww  = (const float*)d_in[1];
  const float* dwb  = (const float*)d_in[2];
  const float* lng  = (const float*)d_in[3];
  const float* lnb  = (const float*)d_in[4];
  const float* w1   = (const float*)d_in[5];
  const float* b1   = (const float*)d_in[6];
  const float* grng = (const float*)d_in[7];
  const float* grnb = (const float*)d_in[8];
  const float* w2   = (const float*)d_in[9];
  const float* b2   = (const float*)d_in[10];
  float* out = (float*)d_out;

  char* ws = (char*)d_ws;
  size_t off = 0;
  auto alloc = [&](size_t bytes) {
    char* p = ws + off;
    off += (bytes + 255) & ~(size_t)255;
    return p;
  };
  unsigned short* y1f  = (unsigned short*)alloc((size_t)M_TOT * 384 * 2);
  unsigned short* convb = (unsigned short*)alloc((size_t)M_TOT * 96 * 2);
  unsigned short* B1sw = (unsigned short*)alloc((size_t)384 * 96 * 2);
  unsigned short* B2sw = (unsigned short*)alloc((size_t)96 * 384 * 2);
  float* gx2  = (float*)alloc((size_t)64 * 384 * 4);
  float* b2p  = (float*)alloc((size_t)96 * 4);
  if (off > ws_size) return;
  // B2s (per-image scaled w2 frags, 4.7 MB) aliases convb: conv is dead
  // after k2f, and k3 (the writer) runs after k2f.
  unsigned short* B2s = convb;

  hipMemsetAsync(gx2, 0, 64 * 384 * 4, stream);
  k0_swz<<<18, 256, 0, stream>>>(w1, B1sw, 384, 96);
  k0_swz<<<18, 256, 0, stream>>>(w2, B2sw, 96, 384);
  k0_b2p<<<1, 128, 0, stream>>>(w2, grnb, b2, b2p);
  k1a_dwconv<<<dim3(96, 64), 256, 0, stream>>>(x, dww, dwb, convb);
  k2f_lngemm1<<<3136, 256, 0, stream>>>(convb, lng, lnb, B1sw, b1, y1f, gx2);
  k3_coefB<<<64, 256, 0, stream>>>(gx2, grng, B2sw, B2s);
  k4_gemm2<<<3136, 256, 0, stream>>>(y1f, B2s, b2p, x, out);
}

// Round 5
// 240.647 us; speedup vs baseline: 1.1023x; 1.1023x over previous
//
#include <hip/hip_runtime.h>
#include <hip/hip_bf16.h>
#include <math.h>

#define HW   3136
#define NIMG 64
#define M_TOT (NIMG * HW)   // 200704

typedef __attribute__((ext_vector_type(8))) short bf16x8_t;
typedef __attribute__((ext_vector_type(4))) float f32x4_t;

__device__ __forceinline__ unsigned short f2bf(float f) {
  union { float f; unsigned u; } v; v.f = f;
  unsigned r = v.u + 0x7FFFu + ((v.u >> 16) & 1u);
  return (unsigned short)(r >> 16);
}
__device__ __forceinline__ float bf2f(unsigned short h) {
  union { unsigned u; float f; } v; v.u = ((unsigned)h) << 16;
  return v.f;
}

// ---------------- K0: swizzle weight [N][K] into MFMA B-fragment order ----
// frag fi = nt*(K/32)+kt ; element j of lane l <-> n = nt*16+(l&15),
// k = kt*32 + (l>>4)*8 + j.
__global__ void k0_swz(const float* __restrict__ wsrc, unsigned short* __restrict__ bsw,
                       int N, int K) {
  int idx = blockIdx.x * 256 + threadIdx.x;
  int total = (N / 16) * (K / 32) * 64;
  if (idx >= total) return;
  int l  = idx & 63;
  int fi = idx >> 6;
  int KT = K / 32;
  int nt = fi / KT, kt = fi - nt * KT;
  int nn = nt * 16 + (l & 15);
  int kb = kt * 32 + (l >> 4) * 8;
  const float* src = wsrc + (size_t)nn * K + kb;
  unsigned short* dst = bsw + (size_t)idx * 8;
#pragma unroll
  for (int j = 0; j < 8; j++) dst[j] = f2bf(src[j]);
}

// ---------------- K0c: fold GRN beta through w2 into bias ---------------
__global__ void k0_b2p(const float* __restrict__ w2, const float* __restrict__ grnb,
                       const float* __restrict__ b2, float* __restrict__ b2p) {
  int c = blockIdx.x * blockDim.x + threadIdx.x;
  if (c >= 96) return;
  float s = b2[c];
  const float* wr = w2 + (size_t)c * 384;
  for (int f = 0; f < 384; f++) s += grnb[f] * wr[f];
  b2p[c] = s;
}

// ---------------- K1a: depthwise 7x7 conv, one (n,c) plane per block ----
// thread -> 4x4 output tile; 10x10 window read as b128/b64 vector LDS reads.
__global__ __launch_bounds__(256) void k1a_dwconv(
    const float* __restrict__ x, const float* __restrict__ dww,
    const float* __restrict__ dwb, unsigned short* __restrict__ conv) {
  __shared__ float xs[62][68];   // row 272 B (16B-aligned)
  const int c = blockIdx.x, n = blockIdx.y;
  const int t = threadIdx.x;
  const float* xp = x + ((size_t)n * 96 + c) * HW;
  for (int i = t; i < 62 * 64; i += 256) {
    int r = i >> 6, col = i & 63;
    if (col < 62) {
      int h = r - 3, w = col - 3;
      xs[r][col] = ((unsigned)h < 56u && (unsigned)w < 56u) ? xp[h * 56 + w] : 0.f;
    }
  }
  float wt[49];
#pragma unroll
  for (int j = 0; j < 49; j++) wt[j] = dww[c * 49 + j];   // uniform -> SGPR
  const float bias = dwb[c];
  __syncthreads();
  if (t >= 196) return;
  const int ty = t / 14, tx = t - ty * 14;
  float acc[4][4];
#pragma unroll
  for (int py = 0; py < 4; py++)
#pragma unroll
    for (int px = 0; px < 4; px++) acc[py][px] = bias;
#pragma unroll
  for (int rr = 0; rr < 10; rr++) {
    float row[10];
    const float* rp = &xs[ty * 4 + rr][tx * 4];
    *(float4*)&row[0] = *(const float4*)rp;
    *(float4*)&row[4] = *(const float4*)(rp + 4);
    *(float2*)&row[8] = *(const float2*)(rp + 8);
#pragma unroll
    for (int py = 0; py < 4; py++) {
      if (py <= rr && rr <= py + 6) {
        const int dy = rr - py;
#pragma unroll
        for (int px = 0; px < 4; px++)
#pragma unroll
          for (int dx = 0; dx < 7; dx++)
            acc[py][px] = fmaf(wt[dy * 7 + dx], row[px + dx], acc[py][px]);
      }
    }
  }
  unsigned short* op = conv + ((size_t)n * 96 + c) * HW + (size_t)(ty * 4) * 56 + tx * 4;
#pragma unroll
  for (int py = 0; py < 4; py++) {
    ushort4 o;
    o.x = f2bf(acc[py][0]); o.y = f2bf(acc[py][1]);
    o.z = f2bf(acc[py][2]); o.w = f2bf(acc[py][3]);
    *(ushort4*)(op + (size_t)py * 56) = o;
  }
}

// ------- K2f: transpose + LN + GEMM1 + GELU + gx2, y1 in FRAG-MAJOR -----
// Two half-feature passes through a small yt buffer (occupancy).
__global__ __launch_bounds__(256) void k2f_lngemm1(
    const unsigned short* __restrict__ conv, const float* __restrict__ lng,
    const float* __restrict__ lnb, const unsigned short* __restrict__ B1,
    const float* __restrict__ b1, unsigned short* __restrict__ y1f,
    float* __restrict__ gx2) {
  __shared__ unsigned short smbuf[64 * 200];   // 25.6 KB; ts (64x104) aliases yt (64x200)
  unsigned short (*ts)[104] = (unsigned short(*)[104])smbuf;
  unsigned short (*yt)[200] = (unsigned short(*)[200])smbuf;
  __shared__ float lnp[192];
  const int t = threadIdx.x;
  const int bid = blockIdx.x;
  const int n = bid / 49;
  const int hw0 = (bid - n * 49) * 64;
  if (t < 192) lnp[t] = (t < 96) ? lng[t] : lnb[t - 96];
  const unsigned short* cp0 = conv + (size_t)n * 96 * HW + hw0;
  for (int i = t; i < 96 * 32; i += 256) {
    int c = i >> 5, pxq = i & 31;
    unsigned u = *(const unsigned*)(cp0 + (size_t)c * HW + pxq * 2);
    ts[pxq * 2 + 0][c] = (unsigned short)(u & 0xffffu);
    ts[pxq * 2 + 1][c] = (unsigned short)(u >> 16);
  }
  __syncthreads();
  // ---- LayerNorm: 4 threads per pixel ----
  {
    const int px = t >> 2, q = t & 3;
    unsigned vu[12];
    float s = 0.f, ss = 0.f;
#pragma unroll
    for (int j = 0; j < 12; j++) {
      vu[j] = *(const unsigned*)&ts[px][q * 24 + j * 2];
      float v0 = bf2f((unsigned short)(vu[j] & 0xffffu));
      float v1 = bf2f((unsigned short)(vu[j] >> 16));
      s += v0 + v1; ss += v0 * v0 + v1 * v1;
    }
    s  += __shfl_xor(s, 1);  s  += __shfl_xor(s, 2);
    ss += __shfl_xor(ss, 1); ss += __shfl_xor(ss, 2);
    float mu  = s * (1.f / 96.f);
    float var = ss * (1.f / 96.f) - mu * mu;
    float rs  = rsqrtf(var + 1e-6f);
#pragma unroll
    for (int j = 0; j < 12; j++) {
      int ch = q * 24 + j * 2;
      float v0 = bf2f((unsigned short)(vu[j] & 0xffffu));
      float v1 = bf2f((unsigned short)(vu[j] >> 16));
      float o0 = (v0 - mu) * rs * lnp[ch] + lnp[96 + ch];
      float o1 = (v1 - mu) * rs * lnp[ch + 1] + lnp[96 + ch + 1];
      *(unsigned*)&ts[px][ch] = (unsigned)f2bf(o0) | ((unsigned)f2bf(o1) << 16);
    }
  }
  __syncthreads();
  // ---- A fragments from ts ----
  const int wv = t >> 6, l = t & 63;
  const int lg = l >> 4, lr = l & 15;
  bf16x8_t af[4][3];
#pragma unroll
  for (int mt = 0; mt < 4; mt++)
#pragma unroll
    for (int kt = 0; kt < 3; kt++)
      af[mt][kt] = *(const bf16x8_t*)&ts[mt * 16 + lr][kt * 32 + lg * 8];
  __syncthreads();   // ts reads drained before yt writes (aliased)

  // ---- GEMM1 + GELU(tanh-form) + gx2, two half-feature passes ----
  for (int half = 0; half < 2; half++) {
    for (int i = 0; i < 3; i++) {
      const int ntl = wv * 3 + i;          // 0..11 within half
      const int nt  = half * 12 + ntl;     // global 16-feature tile
      bf16x8_t bf[3];
#pragma unroll
      for (int kt = 0; kt < 3; kt++)
        bf[kt] = *(const bf16x8_t*)(B1 + ((size_t)(nt * 3 + kt) * 64 + l) * 8);
      f32x4_t acc[4];
#pragma unroll
      for (int mt = 0; mt < 4; mt++) {
        f32x4_t a = {0.f, 0.f, 0.f, 0.f};
#pragma unroll
        for (int kt = 0; kt < 3; kt++)
          a = __builtin_amdgcn_mfma_f32_16x16x32_bf16(af[mt][kt], bf[kt], a, 0, 0, 0);
        acc[mt] = a;
      }
      const int f0 = nt * 16, fl0 = ntl * 16;
      float bias = b1[f0 + lr];
      float s2 = 0.f;
#pragma unroll
      for (int mt = 0; mt < 4; mt++) {
#pragma unroll
        for (int r = 0; r < 4; r++) {
          float v = acc[mt][r] + bias;
          // exact-tanh GELU: g = v * sigmoid(2*0.7978845608*v*(1+0.044715 v^2))
          float sq = v * v;
          float pe = fmaf(sq, -0.0713548163f, -1.5957691216f);
          float e  = __expf(v * pe);
          float g  = v * __builtin_amdgcn_rcpf(1.f + e);
          s2 += g * g;
          yt[mt * 16 + lg * 4 + r][fl0 + lr] = f2bf(g);
        }
      }
      s2 += __shfl_xor(s2, 16);
      s2 += __shfl_xor(s2, 32);
      if (l < 16) atomicAdd(gx2 + n * 384 + f0 + l, s2);
    }
    __syncthreads();
    // frag-major readout of this half (kt = half*6 .. half*6+5)
#pragma unroll
    for (int it = 0; it < 6; it++) {
      int id = t + it * 256;               // 1536 = 4 mt * 6 ktl * 64 l
      int mt = id / 384, ktl = (id >> 6) % 6, ll = id & 63;
      uint4 d = *(const uint4*)&yt[mt * 16 + (ll & 15)][ktl * 32 + (ll >> 4) * 8];
      *(uint4*)(y1f + (((size_t)(bid * 4 + mt) * 12 + half * 6 + ktl) * 64 + ll) * 8) = d;
    }
    __syncthreads();
  }
}

// -------- K3: GRN coefficients + per-image scaled B2 fragments ----------
__global__ __launch_bounds__(256) void k3_coefB(
    const float* __restrict__ gx2, const float* __restrict__ grng,
    const unsigned short* __restrict__ B2, unsigned short* __restrict__ B2s) {
  __shared__ float red[256];
  __shared__ float cf[384];
  const int n = blockIdx.x, t = threadIdx.x;
  float s = 0.f;
  for (int f = t; f < 384; f += 256) {
    float g = sqrtf(gx2[n * 384 + f]);
    cf[f] = g; s += g;
  }
  red[t] = s; __syncthreads();
  for (int o = 128; o > 0; o >>= 1) {
    if (t < o) red[t] += red[t + o];
    __syncthreads();
  }
  float inv = 1.f / (red[0] * (1.f / 384.f) + 1e-6f);
  for (int f = t; f < 384; f += 256)
    cf[f] = 1.f + grng[f] * cf[f] * inv;
  __syncthreads();
  unsigned short* dstn = B2s + (size_t)n * 36864;
  for (int i = t; i < 4608; i += 256) {        // 4608 uint4 = 36864 elems
    int e0 = i * 8;
    int fi = e0 >> 9, ll = (e0 & 511) >> 3;
    int kb = (fi % 12) * 32 + (ll >> 4) * 8;
    uint4 w = *(const uint4*)(B2 + e0);
    const unsigned* wu = (const unsigned*)&w;
    uint4 o;
    unsigned* ou = (unsigned*)&o;
#pragma unroll
    for (int h = 0; h < 4; h++) {
      float v0 = bf2f((unsigned short)(wu[h] & 0xffffu)) * cf[kb + h * 2];
      float v1 = bf2f((unsigned short)(wu[h] >> 16)) * cf[kb + h * 2 + 1];
      ou[h] = (unsigned)f2bf(v0) | ((unsigned)f2bf(v1) << 16);
    }
    *(uint4*)(dstn + e0) = o;
  }
}

// ---------------- K4: GEMM2 (M x 96 x 384) + residual -------------------
__global__ __launch_bounds__(256) void k4_gemm2(
    const unsigned short* __restrict__ y1f, const unsigned short* __restrict__ B2s,
    const float* __restrict__ b2p, const float* __restrict__ x,
    float* __restrict__ out) {
  __shared__ float zt[96][68];
  const int t  = threadIdx.x;
  const int wv = t >> 6, l = t & 63;
  const int lg = l >> 4, lr = l & 15;
  const int m0 = blockIdx.x * 64;
  const int n  = m0 / HW, hw0 = m0 - n * HW;
  const unsigned short* Bn = B2s + (size_t)n * 36864;

  bf16x8_t af[12];
  const unsigned short* ap = y1f + ((size_t)(blockIdx.x * 4 + wv) * 12) * 512 + l * 8;
#pragma unroll
  for (int kt = 0; kt < 12; kt++)
    af[kt] = *(const bf16x8_t*)(ap + kt * 512);

  f32x4_t acc[6];
#pragma unroll
  for (int i = 0; i < 6; i++) acc[i] = (f32x4_t){0.f, 0.f, 0.f, 0.f};
#pragma unroll
  for (int kt = 0; kt < 12; kt++) {
#pragma unroll
    for (int nt = 0; nt < 6; nt++) {
      bf16x8_t b = *(const bf16x8_t*)(Bn + ((size_t)(nt * 12 + kt) * 64 + l) * 8);
      acc[nt] = __builtin_amdgcn_mfma_f32_16x16x32_bf16(af[kt], b, acc[nt], 0, 0, 0);
    }
  }
#pragma unroll
  for (int nt = 0; nt < 6; nt++) {
    int c = nt * 16 + lr;
#pragma unroll
    for (int r = 0; r < 4; r++)
      zt[c][wv * 16 + lg * 4 + r] = acc[nt][r];
  }
  __syncthreads();
#pragma unroll
  for (int it = 0; it < 6; it++) {
    int id = t + it * 256;  // 1536 = 96 c * 16 quads
    int c = id >> 4, mq = id & 15;
    float4 z = *(const float4*)&zt[c][mq * 4];
    size_t base = ((size_t)(n * 96 + c)) * HW + hw0 + mq * 4;
    float4 xv = *(const float4*)(x + base);
    float bp = b2p[c];
    float4 o;
    o.x = xv.x + z.x + bp;
    o.y = xv.y + z.y + bp;
    o.z = xv.z + z.z + bp;
    o.w = xv.w + z.w + bp;
    *(float4*)(out + base) = o;
  }
}

// ---------------- launch -----------------------------------------------
extern "C" void kernel_launch(void* const* d_in, const int* in_sizes, int n_in,
                              void* d_out, int out_size, void* d_ws, size_t ws_size,
                              hipStream_t stream) {
  const float* x    = (const float*)d_in[0];
  const float* dww  = (const float*)d_in[1];
  const float* dwb  = (const float*)d_in[2];
  const float* lng  = (const float*)d_in[3];
  const float* lnb  = (const float*)d_in[4];
  const float* w1   = (const float*)d_in[5];
  const float* b1   = (const float*)d_in[6];
  const float* grng = (const float*)d_in[7];
  const float* grnb = (const float*)d_in[8];
  const float* w2   = (const float*)d_in[9];
  const float* b2   = (const float*)d_in[10];
  float* out = (float*)d_out;

  char* ws = (char*)d_ws;
  size_t off = 0;
  auto alloc = [&](size_t bytes) {
    char* p = ws + off;
    off += (bytes + 255) & ~(size_t)255;
    return p;
  };
  unsigned short* y1f  = (unsigned short*)alloc((size_t)M_TOT * 384 * 2);
  unsigned short* convb = (unsigned short*)alloc((size_t)M_TOT * 96 * 2);
  unsigned short* B1sw = (unsigned short*)alloc((size_t)384 * 96 * 2);
  unsigned short* B2sw = (unsigned short*)alloc((size_t)96 * 384 * 2);
  float* gx2  = (float*)alloc((size_t)64 * 384 * 4);
  float* b2p  = (float*)alloc((size_t)96 * 4);
  if (off > ws_size) return;
  // B2s (per-image scaled w2 frags, 4.7 MB) aliases convb (dead after k2f).
  unsigned short* B2s = convb;

  hipMemsetAsync(gx2, 0, 64 * 384 * 4, stream);
  k0_swz<<<18, 256, 0, stream>>>(w1, B1sw, 384, 96);
  k0_swz<<<18, 256, 0, stream>>>(w2, B2sw, 96, 384);
  k0_b2p<<<1, 128, 0, stream>>>(w2, grnb, b2, b2p);
  k1a_dwconv<<<dim3(96, 64), 256, 0, stream>>>(x, dww, dwb, convb);
  k2f_lngemm1<<<3136, 256, 0, stream>>>(convb, lng, lnb, B1sw, b1, y1f, gx2);
  k3_coefB<<<64, 256, 0, stream>>>(gx2, grng, B2sw, B2s);
  k4_gemm2<<<3136, 256, 0, stream>>>(y1f, B2s, b2p, x, out);
}

// Round 6
// 239.956 us; speedup vs baseline: 1.1054x; 1.0029x over previous
//
#include <hip/hip_runtime.h>
#include <hip/hip_bf16.h>
#include <math.h>

#define HW   3136
#define NIMG 64
#define M_TOT (NIMG * HW)   // 200704

typedef __attribute__((ext_vector_type(8))) short bf16x8_t;
typedef __attribute__((ext_vector_type(4))) float f32x4_t;

__device__ __forceinline__ unsigned short f2bf(float f) {
  union { float f; unsigned u; } v; v.f = f;
  unsigned r = v.u + 0x7FFFu + ((v.u >> 16) & 1u);
  return (unsigned short)(r >> 16);
}
__device__ __forceinline__ float bf2f(unsigned short h) {
  union { unsigned u; float f; } v; v.u = ((unsigned)h) << 16;
  return v.f;
}

// ---------------- K0: swizzle weight [N][K] into MFMA B-fragment order ----
// frag fi = nt*(K/32)+kt ; element j of lane l <-> n = nt*16+(l&15),
// k = kt*32 + (l>>4)*8 + j.
__global__ void k0_swz(const float* __restrict__ wsrc, unsigned short* __restrict__ bsw,
                       int N, int K) {
  int idx = blockIdx.x * 256 + threadIdx.x;
  int total = (N / 16) * (K / 32) * 64;
  if (idx >= total) return;
  int l  = idx & 63;
  int fi = idx >> 6;
  int KT = K / 32;
  int nt = fi / KT, kt = fi - nt * KT;
  int nn = nt * 16 + (l & 15);
  int kb = kt * 32 + (l >> 4) * 8;
  const float* src = wsrc + (size_t)nn * K + kb;
  unsigned short* dst = bsw + (size_t)idx * 8;
#pragma unroll
  for (int j = 0; j < 8; j++) dst[j] = f2bf(src[j]);
}

// ---------------- K0c: fold GRN beta through w2 into bias ---------------
__global__ void k0_b2p(const float* __restrict__ w2, const float* __restrict__ grnb,
                       const float* __restrict__ b2, float* __restrict__ b2p) {
  int c = blockIdx.x * blockDim.x + threadIdx.x;
  if (c >= 96) return;
  float s = b2[c];
  const float* wr = w2 + (size_t)c * 384;
  for (int f = 0; f < 384; f++) s += grnb[f] * wr[f];
  b2p[c] = s;
}

// ---------------- K1a: depthwise 7x7 conv ------------------------------
// Block (128 thr) = one (n,c) plane, one 28-col half. Thread = 4x4 tile.
// tx = t&7 (bank-quad-distinct within every 8-lane group -> conflict-free
// ds_read_b128), ty = t>>3. xs row stride 36 floats (144 B, 16B-aligned).
__global__ __launch_bounds__(128) void k1a_dwconv(
    const float* __restrict__ x, const float* __restrict__ dww,
    const float* __restrict__ dwb, unsigned short* __restrict__ conv) {
  __shared__ float xs[62][36];   // 8.9 KB
  const int c = blockIdx.x, h2 = blockIdx.y, n = blockIdx.z;
  const int x0 = h2 * 28;        // output cols x0 .. x0+27
  const int t = threadIdx.x;
  const float* xp = x + ((size_t)n * 96 + c) * HW;
  // stage rows -3..58, cols x0-3 .. x0+30 (34 cols)
  for (int i = t; i < 62 * 34; i += 128) {
    int r = i / 34, col = i - r * 34;
    int hh = r - 3, ww = x0 + col - 3;
    xs[r][col] = ((unsigned)hh < 56u && (unsigned)ww < 56u) ? xp[hh * 56 + ww] : 0.f;
  }
  float wt[49];
#pragma unroll
  for (int j = 0; j < 49; j++) wt[j] = dww[c * 49 + j];   // uniform -> SGPR
  const float bias = dwb[c];
  __syncthreads();
  const int tx = t & 7, ty = t >> 3;     // ty 0..15, tx 0..7
  if (ty >= 14 || tx >= 7) return;
  float acc[4][4];
#pragma unroll
  for (int py = 0; py < 4; py++)
#pragma unroll
    for (int px = 0; px < 4; px++) acc[py][px] = bias;
#pragma unroll
  for (int rr = 0; rr < 10; rr++) {
    float row[12];
    const float* rp = &xs[ty * 4 + rr][tx * 4];
    *(float4*)&row[0] = *(const float4*)rp;
    *(float4*)&row[4] = *(const float4*)(rp + 4);
    *(float4*)&row[8] = *(const float4*)(rp + 8);
#pragma unroll
    for (int py = 0; py < 4; py++) {
      if (py <= rr && rr <= py + 6) {
        const int dy = rr - py;
#pragma unroll
        for (int px = 0; px < 4; px++)
#pragma unroll
          for (int dx = 0; dx < 7; dx++)
            acc[py][px] = fmaf(wt[dy * 7 + dx], row[px + dx], acc[py][px]);
      }
    }
  }
  unsigned short* op = conv + ((size_t)n * 96 + c) * HW + (size_t)(ty * 4) * 56 + x0 + tx * 4;
#pragma unroll
  for (int py = 0; py < 4; py++) {
    ushort4 o;
    o.x = f2bf(acc[py][0]); o.y = f2bf(acc[py][1]);
    o.z = f2bf(acc[py][2]); o.w = f2bf(acc[py][3]);
    *(ushort4*)(op + (size_t)py * 56) = o;
  }
}

// ------- K2f: transpose + LN + GEMM1 + GELU + gx2, y1 in FRAG-MAJOR -----
// Two half-feature passes through a small yt buffer (occupancy).
__global__ __launch_bounds__(256) void k2f_lngemm1(
    const unsigned short* __restrict__ conv, const float* __restrict__ lng,
    const float* __restrict__ lnb, const unsigned short* __restrict__ B1,
    const float* __restrict__ b1, unsigned short* __restrict__ y1f,
    float* __restrict__ gx2) {
  __shared__ unsigned short smbuf[64 * 200];   // 25.6 KB; ts (64x104) aliases yt (64x200)
  unsigned short (*ts)[104] = (unsigned short(*)[104])smbuf;
  unsigned short (*yt)[200] = (unsigned short(*)[200])smbuf;
  __shared__ float lnp[192];
  const int t = threadIdx.x;
  const int bid = blockIdx.x;
  const int n = bid / 49;
  const int hw0 = (bid - n * 49) * 64;
  if (t < 192) lnp[t] = (t < 96) ? lng[t] : lnb[t - 96];
  const unsigned short* cp0 = conv + (size_t)n * 96 * HW + hw0;
  for (int i = t; i < 96 * 32; i += 256) {
    int c = i >> 5, pxq = i & 31;
    unsigned u = *(const unsigned*)(cp0 + (size_t)c * HW + pxq * 2);
    ts[pxq * 2 + 0][c] = (unsigned short)(u & 0xffffu);
    ts[pxq * 2 + 1][c] = (unsigned short)(u >> 16);
  }
  __syncthreads();
  // ---- LayerNorm: 4 threads per pixel ----
  {
    const int px = t >> 2, q = t & 3;
    unsigned vu[12];
    float s = 0.f, ss = 0.f;
#pragma unroll
    for (int j = 0; j < 12; j++) {
      vu[j] = *(const unsigned*)&ts[px][q * 24 + j * 2];
      float v0 = bf2f((unsigned short)(vu[j] & 0xffffu));
      float v1 = bf2f((unsigned short)(vu[j] >> 16));
      s += v0 + v1; ss += v0 * v0 + v1 * v1;
    }
    s  += __shfl_xor(s, 1);  s  += __shfl_xor(s, 2);
    ss += __shfl_xor(ss, 1); ss += __shfl_xor(ss, 2);
    float mu  = s * (1.f / 96.f);
    float var = ss * (1.f / 96.f) - mu * mu;
    float rs  = rsqrtf(var + 1e-6f);
#pragma unroll
    for (int j = 0; j < 12; j++) {
      int ch = q * 24 + j * 2;
      float v0 = bf2f((unsigned short)(vu[j] & 0xffffu));
      float v1 = bf2f((unsigned short)(vu[j] >> 16));
      float o0 = (v0 - mu) * rs * lnp[ch] + lnp[96 + ch];
      float o1 = (v1 - mu) * rs * lnp[ch + 1] + lnp[96 + ch + 1];
      *(unsigned*)&ts[px][ch] = (unsigned)f2bf(o0) | ((unsigned)f2bf(o1) << 16);
    }
  }
  __syncthreads();
  // ---- A fragments from ts ----
  const int wv = t >> 6, l = t & 63;
  const int lg = l >> 4, lr = l & 15;
  bf16x8_t af[4][3];
#pragma unroll
  for (int mt = 0; mt < 4; mt++)
#pragma unroll
    for (int kt = 0; kt < 3; kt++)
      af[mt][kt] = *(const bf16x8_t*)&ts[mt * 16 + lr][kt * 32 + lg * 8];
  __syncthreads();   // ts reads drained before yt writes (aliased)

  // ---- GEMM1 + GELU(tanh-form) + gx2, two half-feature passes ----
  for (int half = 0; half < 2; half++) {
    for (int i = 0; i < 3; i++) {
      const int ntl = wv * 3 + i;          // 0..11 within half
      const int nt  = half * 12 + ntl;     // global 16-feature tile
      bf16x8_t bf[3];
#pragma unroll
      for (int kt = 0; kt < 3; kt++)
        bf[kt] = *(const bf16x8_t*)(B1 + ((size_t)(nt * 3 + kt) * 64 + l) * 8);
      f32x4_t acc[4];
#pragma unroll
      for (int mt = 0; mt < 4; mt++) {
        f32x4_t a = {0.f, 0.f, 0.f, 0.f};
#pragma unroll
        for (int kt = 0; kt < 3; kt++)
          a = __builtin_amdgcn_mfma_f32_16x16x32_bf16(af[mt][kt], bf[kt], a, 0, 0, 0);
        acc[mt] = a;
      }
      const int f0 = nt * 16, fl0 = ntl * 16;
      float bias = b1[f0 + lr];
      float s2 = 0.f;
#pragma unroll
      for (int mt = 0; mt < 4; mt++) {
#pragma unroll
        for (int r = 0; r < 4; r++) {
          float v = acc[mt][r] + bias;
          // exact-tanh GELU: g = v * sigmoid(1.5957691 v + 0.0713548 v^3)
          float sq = v * v;
          float pe = fmaf(sq, -0.0713548163f, -1.5957691216f);
          float e  = __expf(v * pe);
          float g  = v * __builtin_amdgcn_rcpf(1.f + e);
          s2 += g * g;
          yt[mt * 16 + lg * 4 + r][fl0 + lr] = f2bf(g);
        }
      }
      s2 += __shfl_xor(s2, 16);
      s2 += __shfl_xor(s2, 32);
      if (l < 16) atomicAdd(gx2 + n * 384 + f0 + l, s2);
    }
    __syncthreads();
    // frag-major readout of this half (kt = half*6 .. half*6+5)
#pragma unroll
    for (int it = 0; it < 6; it++) {
      int id = t + it * 256;               // 1536 = 4 mt * 6 ktl * 64 l
      int mt = id / 384, ktl = (id >> 6) % 6, ll = id & 63;
      uint4 d = *(const uint4*)&yt[mt * 16 + (ll & 15)][ktl * 32 + (ll >> 4) * 8];
      *(uint4*)(y1f + (((size_t)(bid * 4 + mt) * 12 + half * 6 + ktl) * 64 + ll) * 8) = d;
    }
    __syncthreads();
  }
}

// -------- K3: GRN coefficients + per-image scaled B2 fragments ----------
__global__ __launch_bounds__(256) void k3_coefB(
    const float* __restrict__ gx2, const float* __restrict__ grng,
    const unsigned short* __restrict__ B2, unsigned short* __restrict__ B2s) {
  __shared__ float red[256];
  __shared__ float cf[384];
  const int n = blockIdx.x, t = threadIdx.x;
  float s = 0.f;
  for (int f = t; f < 384; f += 256) {
    float g = sqrtf(gx2[n * 384 + f]);
    cf[f] = g; s += g;
  }
  red[t] = s; __syncthreads();
  for (int o = 128; o > 0; o >>= 1) {
    if (t < o) red[t] += red[t + o];
    __syncthreads();
  }
  float inv = 1.f / (red[0] * (1.f / 384.f) + 1e-6f);
  for (int f = t; f < 384; f += 256)
    cf[f] = 1.f + grng[f] * cf[f] * inv;
  __syncthreads();
  unsigned short* dstn = B2s + (size_t)n * 36864;
  for (int i = t; i < 4608; i += 256) {        // 4608 uint4 = 36864 elems
    int e0 = i * 8;
    int fi = e0 >> 9, ll = (e0 & 511) >> 3;
    int kb = (fi % 12) * 32 + (ll >> 4) * 8;
    uint4 w = *(const uint4*)(B2 + e0);
    const unsigned* wu = (const unsigned*)&w;
    uint4 o;
    unsigned* ou = (unsigned*)&o;
#pragma unroll
    for (int h = 0; h < 4; h++) {
      float v0 = bf2f((unsigned short)(wu[h] & 0xffffu)) * cf[kb + h * 2];
      float v1 = bf2f((unsigned short)(wu[h] >> 16)) * cf[kb + h * 2 + 1];
      ou[h] = (unsigned)f2bf(v0) | ((unsigned)f2bf(v1) << 16);
    }
    *(uint4*)(dstn + e0) = o;
  }
}

// ---------------- K4: GEMM2 (M x 96 x 384) + residual -------------------
__global__ __launch_bounds__(256) void k4_gemm2(
    const unsigned short* __restrict__ y1f, const unsigned short* __restrict__ B2s,
    const float* __restrict__ b2p, const float* __restrict__ x,
    float* __restrict__ out) {
  __shared__ float zt[96][68];
  const int t  = threadIdx.x;
  const int wv = t >> 6, l = t & 63;
  const int lg = l >> 4, lr = l & 15;
  const int m0 = blockIdx.x * 64;
  const int n  = m0 / HW, hw0 = m0 - n * HW;
  const unsigned short* Bn = B2s + (size_t)n * 36864;

  bf16x8_t af[12];
  const unsigned short* ap = y1f + ((size_t)(blockIdx.x * 4 + wv) * 12) * 512 + l * 8;
#pragma unroll
  for (int kt = 0; kt < 12; kt++)
    af[kt] = *(const bf16x8_t*)(ap + kt * 512);

  f32x4_t acc[6];
#pragma unroll
  for (int i = 0; i < 6; i++) acc[i] = (f32x4_t){0.f, 0.f, 0.f, 0.f};
#pragma unroll
  for (int kt = 0; kt < 12; kt++) {
#pragma unroll
    for (int nt = 0; nt < 6; nt++) {
      bf16x8_t b = *(const bf16x8_t*)(Bn + ((size_t)(nt * 12 + kt) * 64 + l) * 8);
      acc[nt] = __builtin_amdgcn_mfma_f32_16x16x32_bf16(af[kt], b, acc[nt], 0, 0, 0);
    }
  }
#pragma unroll
  for (int nt = 0; nt < 6; nt++) {
    int c = nt * 16 + lr;
#pragma unroll
    for (int r = 0; r < 4; r++)
      zt[c][wv * 16 + lg * 4 + r] = acc[nt][r];
  }
  __syncthreads();
#pragma unroll
  for (int it = 0; it < 6; it++) {
    int id = t + it * 256;  // 1536 = 96 c * 16 quads
    int c = id >> 4, mq = id & 15;
    float4 z = *(const float4*)&zt[c][mq * 4];
    size_t base = ((size_t)(n * 96 + c)) * HW + hw0 + mq * 4;
    float4 xv = *(const float4*)(x + base);
    float bp = b2p[c];
    float4 o;
    o.x = xv.x + z.x + bp;
    o.y = xv.y + z.y + bp;
    o.z = xv.z + z.z + bp;
    o.w = xv.w + z.w + bp;
    *(float4*)(out + base) = o;
  }
}

// ---------------- launch -----------------------------------------------
extern "C" void kernel_launch(void* const* d_in, const int* in_sizes, int n_in,
                              void* d_out, int out_size, void* d_ws, size_t ws_size,
                              hipStream_t stream) {
  const float* x    = (const float*)d_in[0];
  const float* dww  = (const float*)d_in[1];
  const float* dwb  = (const float*)d_in[2];
  const float* lng  = (const float*)d_in[3];
  const float* lnb  = (const float*)d_in[4];
  const float* w1   = (const float*)d_in[5];
  const float* b1   = (const float*)d_in[6];
  const float* grng = (const float*)d_in[7];
  const float* grnb = (const float*)d_in[8];
  const float* w2   = (const float*)d_in[9];
  const float* b2   = (const float*)d_in[10];
  float* out = (float*)d_out;

  char* ws = (char*)d_ws;
  size_t off = 0;
  auto alloc = [&](size_t bytes) {
    char* p = ws + off;
    off += (bytes + 255) & ~(size_t)255;
    return p;
  };
  unsigned short* y1f  = (unsigned short*)alloc((size_t)M_TOT * 384 * 2);
  unsigned short* convb = (unsigned short*)alloc((size_t)M_TOT * 96 * 2);
  unsigned short* B1sw = (unsigned short*)alloc((size_t)384 * 96 * 2);
  unsigned short* B2sw = (unsigned short*)alloc((size_t)96 * 384 * 2);
  float* gx2  = (float*)alloc((size_t)64 * 384 * 4);
  float* b2p  = (float*)alloc((size_t)96 * 4);
  if (off > ws_size) return;
  // B2s (per-image scaled w2 frags, 4.7 MB) aliases convb (dead after k2f).
  unsigned short* B2s = convb;

  hipMemsetAsync(gx2, 0, 64 * 384 * 4, stream);
  k0_swz<<<18, 256, 0, stream>>>(w1, B1sw, 384, 96);
  k0_swz<<<18, 256, 0, stream>>>(w2, B2sw, 96, 384);
  k0_b2p<<<1, 128, 0, stream>>>(w2, grnb, b2, b2p);
  k1a_dwconv<<<dim3(96, 2, 64), 128, 0, stream>>>(x, dww, dwb, convb);
  k2f_lngemm1<<<3136, 256, 0, stream>>>(convb, lng, lnb, B1sw, b1, y1f, gx2);
  k3_coefB<<<64, 256, 0, stream>>>(gx2, grng, B2sw, B2s);
  k4_gemm2<<<3136, 256, 0, stream>>>(y1f, B2s, b2p, x, out);
}